// Round 12
// baseline (117.425 us; speedup 1.0000x reference)
//
#include <hip/hip_runtime.h>
#include <stdint.h>
#include <math.h>

typedef __bf16 bf16;
typedef __bf16 bf16x8 __attribute__((ext_vector_type(8)));
typedef __bf16 bf16x4 __attribute__((ext_vector_type(4)));
typedef float f32x4 __attribute__((ext_vector_type(4)));

static constexpr int BATCH = 16384;
static constexpr int D_IN  = 1024;
static constexpr int UNITS = 512;
static constexpr int D_OUT = 512;

__device__ __forceinline__ void gll16(const void* g, void* l) {
    __builtin_amdgcn_global_load_lds(
        (const __attribute__((address_space(1))) void*)g,
        (__attribute__((address_space(3))) void*)l,
        16, 0, 0);
}

template<int N>
__device__ __forceinline__ void waitvm() {
    static_assert(N < 16, "vmcnt imm");
    __builtin_amdgcn_s_waitcnt(0x0F70 | N);
    asm volatile("" ::: "memory");
}
__device__ __forceinline__ void barrier_raw() {
    asm volatile("" ::: "memory");
    __builtin_amdgcn_s_barrier();
    asm volatile("" ::: "memory");
}

// ---------------- weight prep: one launch ----------------
__global__ __launch_bounds__(256)
void k_prep(const float* __restrict__ w_in, const float* __restrict__ sens_w,
            const float* __restrict__ ro_w,
            bf16* __restrict__ w_in_bf, bf16* __restrict__ sensT, bf16* __restrict__ ro_bf)
{
    __shared__ float tile[32][33];
    const int b = blockIdx.x;
    const int t = threadIdx.x;
    if (b < 512) {
        int i = b * 256 + t;
        f32x4 v = ((const f32x4*)w_in)[i];
        bf16x4 o = { (bf16)v.x, (bf16)v.y, (bf16)v.z, (bf16)v.w };
        ((bf16x4*)w_in_bf)[i] = o;
    } else if (b < 768) {
        int bb = b - 512;
        int bx = bb & 15, by = bb >> 4;
        int tx = t & 31, ty = t >> 5;
        #pragma unroll
        for (int j = ty; j < 32; j += 8)
            tile[j][tx] = sens_w[(size_t)(by * 32 + j) * UNITS + bx * 32 + tx];
        __syncthreads();
        #pragma unroll
        for (int j = ty; j < 32; j += 8)
            sensT[(size_t)(bx * 32 + j) * UNITS + by * 32 + tx] = (bf16)tile[tx][j];
    } else {
        int i = (b - 768) * 256 + t;
        f32x4 v = ((const f32x4*)ro_w)[i];
        bf16x4 o = { (bf16)v.x, (bf16)v.y, (bf16)v.z, (bf16)v.w };
        ((bf16x4*)ro_bf)[i] = o;
    }
}

// ============ fully fused network: one 64-row strip per block ============
// Phase 1: proj = tanh(x @ w_in^T + b_in)           (proj -> 64 KB LDS, bf16 swizzled)
// Phase 2: a = sigmoid(proj @ sensT^T + sigma); ns = a + (states-a)*exp(-.1/tau)
//          -> write new_st (global), stash ns bf16 into the same LDS buffer
// Phase 3: out = ns @ ro^T + ro_b
// 512 thr / 8 waves; wave w owns all 64 rows x cols [w*64, w*64+64) (acc 4x4).
// B tiles (512 x 32k bf16 = 32 KB) via gll16, D=2 stage-early ring, counted vmcnt
// (stage(i+1) -> waitvm<L> -> bar -> MFMA -> bar; WAR-safe: stage follows the
//  prior iteration's 2nd barrier). Rule-21 XOR involutions throughout.
__global__ __launch_bounds__(512, 2)
void k_fused(const float* __restrict__ x,
             const bf16* __restrict__ w_in_bf, const float* __restrict__ b_in,
             const bf16* __restrict__ sensT,   const float* __restrict__ sens_sig,
             const bf16* __restrict__ ro_bf,   const float* __restrict__ ro_b,
             const float* __restrict__ tau,    const float* __restrict__ states,
             float* __restrict__ out, float* __restrict__ new_st)
{
    extern __shared__ __align__(16) char smem[];
    char* sA = smem;                 // 2 x 8 KB : x fp32 tile 64x32 (pre-swizzled src)
    char* sB = smem + 16384;         // 2 x 32 KB: B tile 512x32 bf16 (pre-swizzled src)
    char* sP = smem + 81920;         // 64 KB    : proj / nst, [64][512] bf16 swizzled

    const int t = threadIdx.x;
    const int d = blockIdx.x;
    const int bid = (d & 7) * 32 + (d >> 3);      // 256 blocks, XCD swizzle
    const int m0 = bid << 6;

    const int lane = t & 63;
    const int wave = t >> 6;
    const int wc   = wave << 6;
    const int l15  = lane & 15;
    const int lk   = (lane >> 4) << 3;            // k-elem offset of lane's frag
    const int r0   = (lane >> 4) << 2;            // C/D row sub-offset

    // ---- staging constants (pre-swizzled sources, rule 21) ----
    const int brow  = t >> 2;                                  // B: 128 rows/issue x4
    const int bslot = ((t & 3) ^ ((brow >> 1) & 3)) << 4;      // bytes in 64-B window
    const int ar    = t >> 3;                                  // A: 64 rows, 8 slots
    const int aslot = ((t & 7) ^ (ar & 7)) << 4;
    const char* xsrc = (const char*)x + (size_t)(m0 + ar) * (D_IN * 4) + aslot;

    // ---- fragment read offsets ----
    int boff[4];
    #pragma unroll
    for (int n = 0; n < 4; ++n) {
        const int R = wc + n * 16 + l15;
        boff[n] = R * 64 + ((lk * 2) ^ (((R >> 1) & 3) << 4));
    }
    int aoff0[4], aoff1[4], prow[4], pswz[4];
    #pragma unroll
    for (int m = 0; m < 4; ++m) {
        const int R = m * 16 + l15;
        const int s = (R & 7) << 4;
        aoff0[m] = R * 128 + ((lk * 4) ^ s);
        aoff1[m] = R * 128 + ((lk * 4 + 16) ^ s);
        prow[m]  = R * 1024;
        pswz[m]  = R & 7;
    }
    const int pslotk = lk >> 3;                   // 0 or 1

    f32x4 acc[4][4];

    auto zacc = [&]() {
        #pragma unroll
        for (int m = 0; m < 4; ++m)
            #pragma unroll
            for (int n = 0; n < 4; ++n)
                acc[m][n] = (f32x4){0.f, 0.f, 0.f, 0.f};
    };
    auto stageB = [&](int buf, const char* Bb, int kbytes, int kt) {
        const size_t ko = (size_t)kt * 2 + bslot;
        #pragma unroll
        for (int j = 0; j < 4; ++j)
            gll16(Bb + (size_t)(j * 128 + brow) * kbytes + ko,
                  sB + (buf << 15) + (j << 13) + (t << 4));
    };
    auto stageA = [&](int buf, int kt) {
        gll16(xsrc + (size_t)kt * 4, sA + (buf << 13) + (t << 4));
    };

    // ================= phase 1: K = 1024, A = x (fp32, staged) =================
    zacc();
    {
        const char* Bb = (const char*)w_in_bf;
        stageA(0, 0);
        stageB(0, Bb, D_IN * 2, 0);
        for (int i = 0; i < 32; ++i) {
            const int cur = i & 1;
            if (i < 31) {
                stageA(cur ^ 1, (i + 1) * 32);
                stageB(cur ^ 1, Bb, D_IN * 2, (i + 1) * 32);
                waitvm<5>();                      // tile i retired, tile i+1 in flight
            } else {
                waitvm<0>();
            }
            barrier_raw();
            const char* aB = sA + (cur << 13);
            const char* bB = sB + (cur << 15);
            bf16x8 afr[4], bfr[4];
            #pragma unroll
            for (int m = 0; m < 4; ++m) {
                f32x4 h0 = *(const f32x4*)(aB + aoff0[m]);
                f32x4 h1 = *(const f32x4*)(aB + aoff1[m]);
                afr[m] = (bf16x8){ (bf16)h0.x, (bf16)h0.y, (bf16)h0.z, (bf16)h0.w,
                                   (bf16)h1.x, (bf16)h1.y, (bf16)h1.z, (bf16)h1.w };
            }
            #pragma unroll
            for (int n = 0; n < 4; ++n)
                bfr[n] = *(const bf16x8*)(bB + boff[n]);
            #pragma unroll
            for (int m = 0; m < 4; ++m)
                #pragma unroll
                for (int n = 0; n < 4; ++n)
                    acc[m][n] = __builtin_amdgcn_mfma_f32_16x16x32_bf16(
                                    afr[m], bfr[n], acc[m][n], 0, 0, 0);
            barrier_raw();
        }
    }
    // epilogue 1: tanh -> proj (swizzled b16 scatter; waves write disjoint cols)
    #pragma unroll
    for (int n = 0; n < 4; ++n) {
        const int gc = wc + n * 16 + l15;
        const float bv = b_in[gc];
        #pragma unroll
        for (int m = 0; m < 4; ++m)
            #pragma unroll
            for (int r = 0; r < 4; ++r) {
                const int grow = m * 16 + r0 + r;
                float v = acc[m][n][r] + bv;
                float tv = 1.0f - 2.0f / (1.0f + __expf(2.0f * v));
                *(bf16*)(sP + grow * 1024 +
                         ((((gc >> 3) ^ (grow & 7)) << 4) | ((gc & 7) << 1))) = (bf16)tv;
            }
    }
    __syncthreads();

    // ================= phase 2: K = 512, A = proj (LDS) =================
    zacc();
    {
        const char* Bb = (const char*)sensT;
        stageB(0, Bb, UNITS * 2, 0);
        for (int i = 0; i < 16; ++i) {
            const int cur = i & 1;
            if (i < 15) { stageB(cur ^ 1, Bb, UNITS * 2, (i + 1) * 32); waitvm<4>(); }
            else        { waitvm<0>(); }
            barrier_raw();
            const char* bB = sB + (cur << 15);
            bf16x8 afr[4], bfr[4];
            #pragma unroll
            for (int m = 0; m < 4; ++m)
                afr[m] = *(const bf16x8*)(sP + prow[m] +
                            ((((i << 2) + pslotk) ^ pswz[m]) << 4));
            #pragma unroll
            for (int n = 0; n < 4; ++n)
                bfr[n] = *(const bf16x8*)(bB + boff[n]);
            #pragma unroll
            for (int m = 0; m < 4; ++m)
                #pragma unroll
                for (int n = 0; n < 4; ++n)
                    acc[m][n] = __builtin_amdgcn_mfma_f32_16x16x32_bf16(
                                    afr[m], bfr[n], acc[m][n], 0, 0, 0);
            barrier_raw();
        }
    }
    // epilogue 2: sigmoid + ODE; write new_st; keep ns in acc
    #pragma unroll
    for (int n = 0; n < 4; ++n) {
        const int gc = wc + n * 16 + l15;
        const float sg  = sens_sig[gc];
        const float dec = __expf(-0.1f / tau[gc]);
        #pragma unroll
        for (int m = 0; m < 4; ++m)
            #pragma unroll
            for (int r = 0; r < 4; ++r) {
                const int grow = m * 16 + r0 + r;
                float v = acc[m][n][r] + sg;
                float a = 1.0f / (1.0f + __expf(-v));
                float s = states[(size_t)(m0 + grow) * UNITS + gc];
                float ns = a + (s - a) * dec;
                new_st[(size_t)(m0 + grow) * UNITS + gc] = ns;
                acc[m][n][r] = ns;
            }
    }
    __syncthreads();                 // all proj reads done -> safe to overwrite
    #pragma unroll
    for (int n = 0; n < 4; ++n) {
        const int gc = wc + n * 16 + l15;
        #pragma unroll
        for (int m = 0; m < 4; ++m)
            #pragma unroll
            for (int r = 0; r < 4; ++r) {
                const int grow = m * 16 + r0 + r;
                *(bf16*)(sP + grow * 1024 +
                         ((((gc >> 3) ^ (grow & 7)) << 4) | ((gc & 7) << 1)))
                    = (bf16)acc[m][n][r];
            }
    }
    __syncthreads();

    // ================= phase 3: K = 512, A = ns (LDS) =================
    zacc();
    {
        const char* Bb = (const char*)ro_bf;
        stageB(0, Bb, UNITS * 2, 0);
        for (int i = 0; i < 16; ++i) {
            const int cur = i & 1;
            if (i < 15) { stageB(cur ^ 1, Bb, UNITS * 2, (i + 1) * 32); waitvm<4>(); }
            else        { waitvm<0>(); }
            barrier_raw();
            const char* bB = sB + (cur << 15);
            bf16x8 afr[4], bfr[4];
            #pragma unroll
            for (int m = 0; m < 4; ++m)
                afr[m] = *(const bf16x8*)(sP + prow[m] +
                            ((((i << 2) + pslotk) ^ pswz[m]) << 4));
            #pragma unroll
            for (int n = 0; n < 4; ++n)
                bfr[n] = *(const bf16x8*)(bB + boff[n]);
            #pragma unroll
            for (int m = 0; m < 4; ++m)
                #pragma unroll
                for (int n = 0; n < 4; ++n)
                    acc[m][n] = __builtin_amdgcn_mfma_f32_16x16x32_bf16(
                                    afr[m], bfr[n], acc[m][n], 0, 0, 0);
            barrier_raw();
        }
    }
    // epilogue 3: out
    #pragma unroll
    for (int n = 0; n < 4; ++n) {
        const int gc = wc + n * 16 + l15;
        const float rb = ro_b[gc];
        #pragma unroll
        for (int m = 0; m < 4; ++m)
            #pragma unroll
            for (int r = 0; r < 4; ++r) {
                const int grow = m * 16 + r0 + r;
                out[(size_t)(m0 + grow) * D_OUT + gc] = acc[m][n][r] + rb;
            }
    }
}

extern "C" void kernel_launch(void* const* d_in, const int* in_sizes, int n_in,
                              void* d_out, int out_size, void* d_ws, size_t ws_size,
                              hipStream_t stream) {
    const float* x        = (const float*)d_in[0];
    const float* w_in     = (const float*)d_in[1];
    const float* b_in     = (const float*)d_in[2];
    const float* sens_w   = (const float*)d_in[3];
    const float* sens_sig = (const float*)d_in[4];
    const float* tau      = (const float*)d_in[5];
    const float* ro_w     = (const float*)d_in[6];
    const float* ro_b     = (const float*)d_in[7];
    const float* states   = (const float*)d_in[8];

    float* out    = (float*)d_out;                       // [B][D_OUT]
    float* new_st = out + (size_t)BATCH * D_OUT;         // [B][UNITS]

    bf16* w_in_bf = (bf16*)d_ws;                         // 512*1024
    bf16* sensT   = w_in_bf + (size_t)UNITS * D_IN;      // 512*512 (transposed)
    bf16* ro_bf   = sensT + (size_t)UNITS * UNITS;       // 512*512

    k_prep<<<1024, 256, 0, stream>>>(w_in, sens_w, ro_w, w_in_bf, sensT, ro_bf);

    constexpr int SMEM = 16384 + 65536 + 65536;          // 144 KB dynamic LDS
    (void)hipFuncSetAttribute(reinterpret_cast<const void*>(&k_fused),
                              hipFuncAttributeMaxDynamicSharedMemorySize, SMEM);
    k_fused<<<BATCH / 64, 512, SMEM, stream>>>(
        x, w_in_bf, b_in, sensT, sens_sig, ro_bf, ro_b, tau, states, out, new_st);
}

// Round 13
// 80.763 us; speedup vs baseline: 1.4540x; 1.4540x over previous
//
#include <hip/hip_runtime.h>
#include <stdint.h>
#include <math.h>

typedef __bf16 bf16;
typedef __bf16 bf16x8 __attribute__((ext_vector_type(8)));
typedef __bf16 bf16x4 __attribute__((ext_vector_type(4)));
typedef float f32x4 __attribute__((ext_vector_type(4)));

static constexpr int BATCH = 16384;
static constexpr int D_IN  = 1024;
static constexpr int UNITS = 512;
static constexpr int D_OUT = 512;

__device__ __forceinline__ void gll16(const void* g, void* l) {
    __builtin_amdgcn_global_load_lds(
        (const __attribute__((address_space(1))) void*)g,
        (__attribute__((address_space(3))) void*)l,
        16, 0, 0);
}

template<int N>
__device__ __forceinline__ void waitvm() {
    static_assert(N < 16, "vmcnt imm");
    __builtin_amdgcn_s_waitcnt(0x0F70 | N);
    asm volatile("" ::: "memory");
}
__device__ __forceinline__ void barrier_raw() {
    asm volatile("" ::: "memory");
    __builtin_amdgcn_s_barrier();
    asm volatile("" ::: "memory");
}

// ---------------- weight prep: one launch ----------------
__global__ __launch_bounds__(256)
void k_prep(const float* __restrict__ w_in, const float* __restrict__ sens_w,
            const float* __restrict__ ro_w,
            bf16* __restrict__ w_in_bf, bf16* __restrict__ sensT, bf16* __restrict__ ro_bf)
{
    __shared__ float tile[32][33];
    const int b = blockIdx.x;
    const int t = threadIdx.x;
    if (b < 512) {
        int i = b * 256 + t;
        f32x4 v = ((const f32x4*)w_in)[i];
        bf16x4 o = { (bf16)v.x, (bf16)v.y, (bf16)v.z, (bf16)v.w };
        ((bf16x4*)w_in_bf)[i] = o;
    } else if (b < 768) {
        int bb = b - 512;
        int bx = bb & 15, by = bb >> 4;
        int tx = t & 31, ty = t >> 5;
        #pragma unroll
        for (int j = ty; j < 32; j += 8)
            tile[j][tx] = sens_w[(size_t)(by * 32 + j) * UNITS + bx * 32 + tx];
        __syncthreads();
        #pragma unroll
        for (int j = ty; j < 32; j += 8)
            sensT[(size_t)(bx * 32 + j) * UNITS + by * 32 + tx] = (bf16)tile[tx][j];
    } else {
        int i = (b - 768) * 256 + t;
        f32x4 v = ((const f32x4*)ro_w)[i];
        bf16x4 o = { (bf16)v.x, (bf16)v.y, (bf16)v.z, (bf16)v.w };
        ((bf16x4*)ro_bf)[i] = o;
    }
}

// ======== k_g1: GEMM1 with BM=64, BN=256 — halves the logical L3 A-traffic ========
// proj = tanh( x[16384,1024](fp32) @ w_in^T + b ), grid 512 (2 blocks/CU).
// L3-BW model (R12 conclusion): G1 time ~= logical-L3 A bytes / ~5 TB/s.
// BN=128 read each x-strip 4x (268 MB -> 54 us); BN=256 reads it 2x, and the
// XCD swizzle makes the strip's two n-blocks consecutive bids on one XCD
// (co-scheduled -> partial L2 dedup toward 1x). Wave shape = proven 32x64.
// DEPTH=3 counted-vmcnt ring; rule-21 XOR involutions (fp32 A slot^=row&7,
// bf16 B slot^=(row>>1)&3).
__global__ __launch_bounds__(512, 4)
void k_g1(const float* __restrict__ Af, const bf16* __restrict__ Bw,
          const float* __restrict__ bias, bf16* __restrict__ outB)
{
    constexpr int K = 1024, NSTEP = K / 32, L = 3;
    __shared__ __align__(16) char sA[3][8192];    // 64 rows x 128 B (fp32)
    __shared__ __align__(16) char sB[3][16384];   // 256 rows x 64 B (bf16)

    const int t = threadIdx.x;
    const int nwg = gridDim.x;                    // 512
    const int d = blockIdx.x;
    const int bid = (d & 7) * (nwg >> 3) + (d >> 3);
    const int mtile = bid >> 1;
    const int ntile = bid & 1;
    const int m0 = mtile << 6, n0 = ntile << 8;

    const int lane = t & 63;
    const int wave = t >> 6;                      // 2m x 4n, wave = 32x64
    const int wr = (wave >> 2) * 32;
    const int wc = (wave & 3) * 64;
    const int l15 = lane & 15;
    const int lk  = (lane >> 4) * 8;

    f32x4 acc[2][4];
    #pragma unroll
    for (int m = 0; m < 2; ++m)
        #pragma unroll
        for (int n = 0; n < 4; ++n)
            acc[m][n] = (f32x4){0.f, 0.f, 0.f, 0.f};

    // ---- staging (pre-swizzled sources) ----
    const int ar = t >> 3;                        // A: 64 rows x 8 slots, 1 issue
    const int aslot = ((t & 7) ^ (ar & 7)) * 16;
    const char* asrc = (const char*)Af + (size_t)(m0 + ar) * (K * 4) + aslot;
    const int brow = t >> 2;                      // B: 128 rows/issue x 2
    const int bslot = ((t & 3) ^ ((brow >> 1) & 3)) * 16;
    const char* bsrc = (const char*)Bw + (size_t)(n0 + brow) * (K * 2) + bslot;

    auto STAGE = [&](int buf, int kt) {
        gll16(asrc + (size_t)kt * 4, &sA[buf][t * 16]);
        const size_t kb = (size_t)kt * 2;
        gll16(bsrc + kb,                       &sB[buf][t * 16]);
        gll16(bsrc + kb + (size_t)128 * K * 2, &sB[buf][8192 + t * 16]);
    };

    // ---- LDS read offsets (swizzle invariant under +16 rows) ----
    int offA0[2], offA1[2], offB[4];
    #pragma unroll
    for (int m = 0; m < 2; ++m) {
        const int R = wr + m * 16 + l15;
        const int s = (R & 7) << 4;
        offA0[m] = R * 128 + ((lk * 4) ^ s);
        offA1[m] = R * 128 + ((lk * 4 + 16) ^ s);
    }
    #pragma unroll
    for (int n = 0; n < 4; ++n) {
        const int R = wc + n * 16 + l15;
        offB[n] = R * 64 + ((lk * 2) ^ (((R >> 1) & 3) << 4));
    }

    auto COMPUTE = [&](int buf) {
        const char* aB = sA[buf];
        const char* bB = sB[buf];
        bf16x8 afr[2], bfr[4];
        #pragma unroll
        for (int m = 0; m < 2; ++m) {
            f32x4 h0 = *(const f32x4*)(aB + offA0[m]);
            f32x4 h1 = *(const f32x4*)(aB + offA1[m]);
            afr[m] = (bf16x8){ (bf16)h0.x, (bf16)h0.y, (bf16)h0.z, (bf16)h0.w,
                               (bf16)h1.x, (bf16)h1.y, (bf16)h1.z, (bf16)h1.w };
        }
        #pragma unroll
        for (int n = 0; n < 4; ++n)
            bfr[n] = *(const bf16x8*)(bB + offB[n]);
        #pragma unroll
        for (int m = 0; m < 2; ++m)
            #pragma unroll
            for (int n = 0; n < 4; ++n)
                acc[m][n] = __builtin_amdgcn_mfma_f32_16x16x32_bf16(
                                afr[m], bfr[n], acc[m][n], 0, 0, 0);
    };

    // ---- 3-deep ring ----
    STAGE(0, 0); STAGE(1, 32); STAGE(2, 64);
    int buf = 0, kt_stage = 96;
    for (int i = 0; i < NSTEP - 2; ++i) {
        waitvm<2 * L>();
        barrier_raw();
        COMPUTE(buf);
        barrier_raw();
        if (kt_stage < K) { STAGE(buf, kt_stage); kt_stage += 32; }
        buf = (buf == 2) ? 0 : buf + 1;
    }
    waitvm<L>(); barrier_raw(); COMPUTE(buf);
    buf = (buf == 2) ? 0 : buf + 1;
    waitvm<0>(); barrier_raw(); COMPUTE(buf);
    asm volatile("" ::: "memory");

    // epilogue: proj = tanh(acc + bias) -> bf16
    const int rbase = m0 + wr + ((lane >> 4) << 2);
    const int cbase = n0 + wc + l15;
    #pragma unroll
    for (int n = 0; n < 4; ++n) {
        const int gc = cbase + n * 16;
        const float bv = bias[gc];
        #pragma unroll
        for (int m = 0; m < 2; ++m)
            #pragma unroll
            for (int r = 0; r < 4; ++r) {
                const int gr = rbase + m * 16 + r;
                float v = acc[m][n][r] + bv;
                float tv = 1.0f - 2.0f / (1.0f + __expf(2.0f * v));
                outB[(size_t)gr * UNITS + gc] = (bf16)tv;
            }
    }
}

// ---------------- R5's proven 128x128 / 8-wave / 3-deep ring GEMM ----------------
// EPI 2: a=sigmoid(.); out_f32 = a+(states-a)*exp(-0.1/tau)   EPI 3: identity
template<int K, int EPI, bool AF32>
__global__ __launch_bounds__(512, 4)
void k_gemm(const float* __restrict__ Af, const bf16* __restrict__ Ab,
            const bf16* __restrict__ Bw,
            const float* __restrict__ bias,
            const float* __restrict__ tau,
            const float* __restrict__ states,
            float* __restrict__ outF, int M, int N)
{
    constexpr int NSTEP = K / 32;
    constexpr int L = AF32 ? 3 : 2;
    constexpr int ABPB = AF32 ? (128 * 32 * 4) : (128 * 32 * 2);
    __shared__ __align__(16) char sAraw[3][ABPB];
    __shared__ bf16 sB[3][128 * 32];

    const int t = threadIdx.x;
    const int ntiles = N >> 7;
    const int nwg = gridDim.x;
    const int d = blockIdx.x;
    const int bid = (d & 7) * (nwg >> 3) + (d >> 3);
    const int mtile = bid / ntiles;
    const int ntile = bid % ntiles;
    const int m0 = mtile << 7, n0 = ntile << 7;

    const int lane = t & 63;
    const int wave = t >> 6;            // 4m x 2n, wave 32x64
    const int wr = (wave >> 1) * 32;
    const int wc = (wave & 1) * 64;
    const int l15 = lane & 15;
    const int lk  = (lane >> 4) * 8;

    f32x4 acc[2][4];
    #pragma unroll
    for (int m = 0; m < 2; ++m)
        #pragma unroll
        for (int n = 0; n < 4; ++n)
            acc[m][n] = (f32x4){0.f, 0.f, 0.f, 0.f};

    const int brow = t >> 2;
    const int bslot8 = ((t & 3) ^ ((brow >> 1) & 3)) * 8;
    const bf16* bbp = Bw + (size_t)(n0 + brow) * K + bslot8;
    const bf16* abp = AF32 ? nullptr : (Ab + (size_t)(m0 + brow) * K + bslot8);
    const int ar = t >> 3;
    const int aslot16 = ((t & 7) ^ (ar & 7)) * 16;
    const char* ag0 = (const char*)Af + (size_t)(m0 + ar) * K * 4 + aslot16;
    const char* ag1 = (const char*)Af + (size_t)(m0 + 64 + ar) * K * 4 + aslot16;

    auto STAGE = [&](int buf, int kt) {
        if constexpr (AF32) {
            gll16(ag0 + (size_t)kt * 4, &sAraw[buf][t * 16]);
            gll16(ag1 + (size_t)kt * 4, &sAraw[buf][8192 + t * 16]);
        } else {
            gll16(abp + kt, &sAraw[buf][t * 16]);
        }
        gll16(bbp + kt, (char*)&sB[buf][0] + t * 16);
    };

    int offB[4];
    #pragma unroll
    for (int n = 0; n < 4; ++n) {
        const int R = wc + n * 16 + l15;
        offB[n] = R * 64 + ((lk * 2) ^ (((R >> 1) & 3) << 4));
    }
    int offA0[2], offA1[2];
    #pragma unroll
    for (int m = 0; m < 2; ++m) {
        const int R = wr + m * 16 + l15;
        if constexpr (AF32) {
            const int s = (R & 7) << 4;
            offA0[m] = R * 128 + ((lk * 4) ^ s);
            offA1[m] = R * 128 + ((lk * 4 + 16) ^ s);
        } else {
            offA0[m] = R * 64 + ((lk * 2) ^ (((R >> 1) & 3) << 4));
        }
    }

    auto COMPUTE = [&](int buf) {
        const char* aB = &sAraw[buf][0];
        const char* bB = (const char*)&sB[buf][0];
        bf16x8 afr[2], bfr[4];
        if constexpr (AF32) {
            #pragma unroll
            for (int m = 0; m < 2; ++m) {
                f32x4 h0 = *(const f32x4*)(aB + offA0[m]);
                f32x4 h1 = *(const f32x4*)(aB + offA1[m]);
                afr[m] = (bf16x8){ (bf16)h0.x, (bf16)h0.y, (bf16)h0.z, (bf16)h0.w,
                                   (bf16)h1.x, (bf16)h1.y, (bf16)h1.z, (bf16)h1.w };
            }
        } else {
            #pragma unroll
            for (int m = 0; m < 2; ++m)
                afr[m] = *(const bf16x8*)(aB + offA0[m]);
        }
        #pragma unroll
        for (int n = 0; n < 4; ++n)
            bfr[n] = *(const bf16x8*)(bB + offB[n]);
        #pragma unroll
        for (int m = 0; m < 2; ++m)
            #pragma unroll
            for (int n = 0; n < 4; ++n)
                acc[m][n] = __builtin_amdgcn_mfma_f32_16x16x32_bf16(
                                afr[m], bfr[n], acc[m][n], 0, 0, 0);
    };

    STAGE(0, 0); STAGE(1, 32); STAGE(2, 64);
    int buf = 0, kt_stage = 96;
    for (int i = 0; i < NSTEP - 2; ++i) {
        waitvm<2 * L>();
        barrier_raw();
        COMPUTE(buf);
        barrier_raw();
        if (kt_stage < K) { STAGE(buf, kt_stage); kt_stage += 32; }
        buf = (buf == 2) ? 0 : buf + 1;
    }
    waitvm<L>(); barrier_raw(); COMPUTE(buf);
    buf = (buf == 2) ? 0 : buf + 1;
    waitvm<0>(); barrier_raw(); COMPUTE(buf);
    asm volatile("" ::: "memory");

    const int rbase = m0 + wr + ((lane >> 4) << 2);
    const int cbase = n0 + wc + l15;
    #pragma unroll
    for (int n = 0; n < 4; ++n) {
        const int gc = cbase + n * 16;
        const float bv = bias[gc];
        float dec = 0.f;
        if constexpr (EPI == 2) dec = __expf(-0.1f / tau[gc]);
        #pragma unroll
        for (int m = 0; m < 2; ++m) {
            #pragma unroll
            for (int r = 0; r < 4; ++r) {
                const int gr = rbase + m * 16 + r;
                float v = acc[m][n][r] + bv;
                if constexpr (EPI == 2) {
                    float a = 1.0f / (1.0f + __expf(-v));
                    float s = states[(size_t)gr * N + gc];
                    outF[(size_t)gr * N + gc] = a + (s - a) * dec;
                } else {
                    outF[(size_t)gr * N + gc] = v;
                }
            }
        }
    }
}

extern "C" void kernel_launch(void* const* d_in, const int* in_sizes, int n_in,
                              void* d_out, int out_size, void* d_ws, size_t ws_size,
                              hipStream_t stream) {
    const float* x        = (const float*)d_in[0];
    const float* w_in     = (const float*)d_in[1];
    const float* b_in     = (const float*)d_in[2];
    const float* sens_w   = (const float*)d_in[3];
    const float* sens_sig = (const float*)d_in[4];
    const float* tau      = (const float*)d_in[5];
    const float* ro_w     = (const float*)d_in[6];
    const float* ro_b     = (const float*)d_in[7];
    const float* states   = (const float*)d_in[8];

    float* out    = (float*)d_out;                       // [B][D_OUT] (final, GEMM3)
    float* new_st = out + (size_t)BATCH * D_OUT;         // [B][UNITS] (final, GEMM2)
    bf16*  proj   = (bf16*)d_out;                        // temp bf16 in half1

    bf16* w_in_bf = (bf16*)d_ws;                         // 512*1024
    bf16* sensT   = w_in_bf + (size_t)UNITS * D_IN;      // 512*512 (transposed)
    bf16* ro_bf   = sensT + (size_t)UNITS * UNITS;       // 512*512

    k_prep<<<1024, 256, 0, stream>>>(w_in, sens_w, ro_w, w_in_bf, sensT, ro_bf);

    // GEMM1: BN=256 -> x-strip logical L3 traffic halved (the R12 model's lever)
    k_g1<<<(BATCH / 64) * (UNITS / 256), 512, 0, stream>>>(x, w_in_bf, b_in, proj);

    // GEMM2: new_st = sig(proj @ sensT^T + sigma); ODE step (A = proj, L2-hot)
    k_gemm<512, 2, false><<<(BATCH / 128) * (UNITS / 128), 512, 0, stream>>>(
        nullptr, proj, sensT, sens_sig, tau, states, new_st, BATCH, UNITS);

    // GEMM3: out = new_st @ readout^T + ro_b (A = new_st, L2-hot fp32)
    k_gemm<512, 3, true><<<(BATCH / 128) * (D_OUT / 128), 512, 0, stream>>>(
        new_st, nullptr, ro_bf, ro_b, nullptr, nullptr, out, BATCH, D_OUT);
}